// Round 6
// baseline (394.565 us; speedup 1.0000x reference)
//
#include <hip/hip_runtime.h>
#include <hip/hip_bf16.h>

#define NN 5000
#define NE 100000

typedef unsigned short u16;
typedef __attribute__((ext_vector_type(8))) short bf16x8;
typedef __attribute__((ext_vector_type(4))) float f32x4;

__device__ __forceinline__ float silu_f(float x) {
    return x / (1.0f + __expf(-x));
}

__device__ __forceinline__ u16 f2bf(float x) {
    unsigned int u = __float_as_uint(x);
    u += 0x7FFFu + ((u >> 16) & 1u);
    return (u16)(u >> 16);
}
__device__ __forceinline__ float bf2f(u16 h) {
    return __uint_as_float(((unsigned int)h) << 16);
}

// ---------------- x = nf @ W_pre * (1/sqrt(128)) ----------------
__global__ __launch_bounds__(128) void k_pre(const float* __restrict__ nf,
                                             const float* __restrict__ Wpre,
                                             float* __restrict__ x) {
    __shared__ float row[128];
    int n = blockIdx.x;
    int v = threadIdx.x;
    row[v] = nf[(size_t)n * 128 + v];
    __syncthreads();
    float acc = 0.f;
#pragma unroll 16
    for (int u = 0; u < 128; ++u) acc += row[u] * Wpre[u * 128 + v];
    x[(size_t)n * 128 + v] = acc * 0.08838834764831845f;
}

// ---------------- CSR build (int atomics only) ----------------
__global__ void k_count(const int* __restrict__ ei, int* __restrict__ counts) {
    int e = blockIdx.x * blockDim.x + threadIdx.x;
    if (e < NE) atomicAdd(&counts[ei[e]], 1);
}

__global__ __launch_bounds__(256) void k_scan(const int* __restrict__ counts,
                                              int* __restrict__ offsets) {
    __shared__ int part[256];
    int t = threadIdx.x;
    const int CH = 20;
    int lo = t * CH, hi = min(lo + CH, NN);
    int s = 0;
    for (int i = lo; i < hi; ++i) s += counts[i];
    part[t] = s;
    __syncthreads();
    if (t == 0) {
        int run = 0;
        for (int i = 0; i < 256; ++i) { int v = part[i]; part[i] = run; run += v; }
    }
    __syncthreads();
    int run = part[t];
    for (int i = lo; i < hi; ++i) { offsets[i] = run; run += counts[i]; }
    if (t == 0) offsets[NN] = NE;
}

__global__ void k_fill(const int* __restrict__ ei, const int* __restrict__ offsets,
                       int* __restrict__ cursor, int* __restrict__ order) {
    int e = blockIdx.x * blockDim.x + threadIdx.x;
    if (e < NE) {
        int i = ei[e];
        int pos = atomicAdd(&cursor[i], 1);
        order[offsets[i] + pos] = e;
    }
}

// ---------------- weight prep: transpose + bf16 hi/lo split ----------------
__global__ __launch_bounds__(256) void k_wprep(const float* __restrict__ w1,
                                               const float* __restrict__ w2,
                                               const float* __restrict__ w3,
                                               u16* __restrict__ w1h, u16* __restrict__ w1l,
                                               u16* __restrict__ w2h, u16* __restrict__ w2l,
                                               u16* __restrict__ w3h, u16* __restrict__ w3l) {
    int i = blockIdx.x * 256 + threadIdx.x;
    if (i < 4096) {
        int k = i >> 6, n = i & 63;
        float v = w1[i];
        u16 h = f2bf(v), l = f2bf(v - bf2f(h));
        w1h[n * 64 + k] = h; w1l[n * 64 + k] = l;
        v = w2[i];
        h = f2bf(v); l = f2bf(v - bf2f(h));
        w2h[n * 64 + k] = h; w2l[n * 64 + k] = l;
    }
    if (i < 32768) {
        int k = i >> 9, n = i & 511;
        float v = w3[i];
        u16 h = f2bf(v), l = f2bf(v - bf2f(h));
        w3h[n * 64 + k] = h; w3l[n * 64 + k] = l;
    }
}

// Wpost^T hi/lo split: wpt[(p*128 + v)*128 + u]
__global__ __launch_bounds__(256) void k_wpprep(const float* __restrict__ Wpost,
                                                u16* __restrict__ wpth,
                                                u16* __restrict__ wptl) {
    int i = blockIdx.x * 256 + threadIdx.x;   // 65536
    int p = i >> 14, rem = i & 16383, u = rem >> 7, v = rem & 127;
    float val = Wpost[i];
    u16 h = f2bf(val), l = f2bf(val - bf2f(h));
    int o = (p * 128 + v) * 128 + u;
    wpth[o] = h; wptl[o] = l;
}

// ---------------- MFMA MLP layers ----------------
__device__ __forceinline__ void layer_mid(const char* s,
                                          const u16* __restrict__ wh,
                                          const u16* __restrict__ wl,
                                          char* d, int w, int l) {
    const int col = w * 16 + (l & 15);
    bf16x8 Bh[2], Bl[2];
#pragma unroll
    for (int kc = 0; kc < 2; ++kc) {
        Bh[kc] = *(const bf16x8*)(wh + col * 64 + kc * 32 + ((l >> 4) << 3));
        Bl[kc] = *(const bf16x8*)(wl + col * 64 + kc * 32 + ((l >> 4) << 3));
    }
#pragma unroll
    for (int rt = 0; rt < 4; ++rt) {
        const int arow = rt * 16 + (l & 15);
        f32x4 acc = {0.f, 0.f, 0.f, 0.f};
#pragma unroll
        for (int kc = 0; kc < 2; ++kc) {
            int off = (arow * 128 + kc * 64 + ((l >> 4) << 4)) ^ ((arow & 7) << 4);
            bf16x8 a = *(const bf16x8*)(s + off);
            acc = __builtin_amdgcn_mfma_f32_16x16x32_bf16(a, Bh[kc], acc, 0, 0, 0);
            acc = __builtin_amdgcn_mfma_f32_16x16x32_bf16(a, Bl[kc], acc, 0, 0, 0);
        }
#pragma unroll
        for (int r = 0; r < 4; ++r) {
            float v = silu_f(acc[r] * 0.125f);
            int orow = rt * 16 + ((l >> 4) << 2) + r;
            int off = (orow * 128 + col * 2) ^ ((orow & 7) << 4);
            *(u16*)(d + off) = f2bf(v);
        }
    }
}

// 64->512 output layer; store bf16 to global in [e][u][p] order.
__device__ __forceinline__ void layer_out(const char* s,
                                          const u16* __restrict__ wh,
                                          const u16* __restrict__ wl,
                                          u16* __restrict__ we, int base, int w, int l) {
    const int r0 = (w & 1) * 32;
    const int c0 = (w >> 1) * 256;
    bf16x8 A[2][2];
#pragma unroll
    for (int rt = 0; rt < 2; ++rt)
#pragma unroll
        for (int kc = 0; kc < 2; ++kc) {
            int row = r0 + rt * 16 + (l & 15);
            int off = (row * 128 + kc * 64 + ((l >> 4) << 4)) ^ ((row & 7) << 4);
            A[rt][kc] = *(const bf16x8*)(s + off);
        }
    for (int nt = 0; nt < 16; ++nt) {
        const int col = c0 + nt * 16 + (l & 15);
        f32x4 acc[2] = {{0.f, 0.f, 0.f, 0.f}, {0.f, 0.f, 0.f, 0.f}};
#pragma unroll
        for (int kc = 0; kc < 2; ++kc) {
            bf16x8 bh = *(const bf16x8*)(wh + col * 64 + kc * 32 + ((l >> 4) << 3));
            bf16x8 bl = *(const bf16x8*)(wl + col * 64 + kc * 32 + ((l >> 4) << 3));
#pragma unroll
            for (int rt = 0; rt < 2; ++rt) {
                acc[rt] = __builtin_amdgcn_mfma_f32_16x16x32_bf16(A[rt][kc], bh, acc[rt], 0, 0, 0);
                acc[rt] = __builtin_amdgcn_mfma_f32_16x16x32_bf16(A[rt][kc], bl, acc[rt], 0, 0, 0);
            }
        }
        const int up = ((col & 127) << 2) + (col >> 7);   // [u][p] position
#pragma unroll
        for (int rt = 0; rt < 2; ++rt)
#pragma unroll
            for (int r = 0; r < 4; ++r) {
                int row = r0 + rt * 16 + ((l >> 4) << 2) + r;
                int e = base + row;
                if (e < NE) we[(size_t)e * 512 + up] = f2bf(acc[rt][r] * 0.125f);
            }
    }
}

__global__ __launch_bounds__(256) void k_mlp(const float* __restrict__ rb,
                                             const float* __restrict__ w0,
                                             const u16* __restrict__ w1h, const u16* __restrict__ w1l,
                                             const u16* __restrict__ w2h, const u16* __restrict__ w2l,
                                             const u16* __restrict__ w3h, const u16* __restrict__ w3l,
                                             u16* __restrict__ we) {
    __shared__ __align__(16) char hA[8192];
    __shared__ __align__(16) char hB[8192];
    __shared__ float rbs[512];
    const int t = threadIdx.x;
    const int l = t & 63, w = t >> 6;
    const int base = blockIdx.x * 64;

    for (int i = t; i < 512; i += 256) {
        int e = base + (i >> 3);
        rbs[i] = (e < NE) ? rb[(size_t)e * 8 + (i & 7)] : 0.f;
    }
    __syncthreads();

    {
        const int m = t >> 2, n0 = (t & 3) * 16;
        float h[16];
#pragma unroll
        for (int nn = 0; nn < 16; ++nn) h[nn] = 0.f;
#pragma unroll
        for (int k = 0; k < 8; ++k) {
            float r = rbs[m * 8 + k];
            const float* wp = w0 + k * 64 + n0;
#pragma unroll
            for (int nn = 0; nn < 16; ++nn) h[nn] += r * wp[nn];
        }
#pragma unroll
        for (int nn = 0; nn < 16; ++nn) {
            float v = silu_f(h[nn] * 0.35355339059327373f);
            int off = (m * 128 + (n0 + nn) * 2) ^ ((m & 7) << 4);
            *(u16*)(hA + off) = f2bf(v);
        }
    }
    __syncthreads();
    layer_mid(hA, w1h, w1l, hB, w, l);
    __syncthreads();
    layer_mid(hB, w2h, w2l, hA, w, l);
    __syncthreads();
    layer_out(hA, w3h, w3l, we, base, w, l);
}

// ---------------- Phase A: per-node segment sum (1 wave per node) ----------------
__global__ __launch_bounds__(256) void k_gather(const float* __restrict__ x,
                                                const u16* __restrict__ we,
                                                const float* __restrict__ sph,
                                                const int* __restrict__ ej,
                                                const int* __restrict__ offsets,
                                                const int* __restrict__ order,
                                                u16* __restrict__ toth,
                                                u16* __restrict__ totl) {
    const int lane = threadIdx.x & 63;
    const int n = blockIdx.x * 4 + (threadIdx.x >> 6);
    if (n >= NN) return;
    const int s0 = offsets[n], s1 = offsets[n + 1];

    float acc0[16] = {};
    float acc1[16] = {};
    const int PMAP[16] = {0,1,1,1, 2,2,2,2, 2,3,3,3, 3,3,3,3};

    for (int base = s0; base < s1; base += 64) {
        int idx = base + lane;
        int ev = (idx < s1) ? order[idx] : 0;
        int jv = (idx < s1) ? ej[ev] : 0;
        int cnt = min(64, s1 - base);
        for (int i = 0; i < cnt; ++i) {
            int e = __shfl(ev, i);
            int j = __shfl(jv, i);
            const float* xp = x + (size_t)j * 128;
            float xj0 = xp[lane];
            float xj1 = xp[lane + 64];
            const u16* wep = we + (size_t)e * 512;
            ushort4 w0v = *(const ushort4*)(wep + lane * 4);
            ushort4 w1v = *(const ushort4*)(wep + (lane + 64) * 4);
            float a0[4] = {xj0 * bf2f(w0v.x), xj0 * bf2f(w0v.y),
                           xj0 * bf2f(w0v.z), xj0 * bf2f(w0v.w)};
            float a1[4] = {xj1 * bf2f(w1v.x), xj1 * bf2f(w1v.y),
                           xj1 * bf2f(w1v.z), xj1 * bf2f(w1v.w)};
            const float4* Y4 = (const float4*)(sph + (size_t)e * 16);
            float yv[16];
            ((float4*)yv)[0] = Y4[0];
            ((float4*)yv)[1] = Y4[1];
            ((float4*)yv)[2] = Y4[2];
            ((float4*)yv)[3] = Y4[3];
#pragma unroll
            for (int k = 0; k < 16; ++k) {
                acc0[k] += a0[PMAP[k]] * yv[k];
                acc1[k] += a1[PMAP[k]] * yv[k];
            }
        }
    }

#pragma unroll
    for (int k = 0; k < 16; ++k) {
        size_t o = ((size_t)n * 16 + k) * 128;
        u16 h0 = f2bf(acc0[k]);
        toth[o + lane] = h0;
        totl[o + lane] = f2bf(acc0[k] - bf2f(h0));
        u16 h1 = f2bf(acc1[k]);
        toth[o + 64 + lane] = h1;
        totl[o + 64 + lane] = f2bf(acc1[k] - bf2f(h1));
    }
}

// ---------------- Phase B: out[n][v][k] = inv * sum_u Wpost[p(k)][u][v] * tot[n][u][k]
// Wave = (node-quad, vt). Block = 4 waves = (node-quad, v-half). 2500 blocks, 10000 waves.
__global__ __launch_bounds__(256) void k_post(const u16* __restrict__ toth,
                                              const u16* __restrict__ totl,
                                              const u16* __restrict__ wpth,
                                              const u16* __restrict__ wptl,
                                              float* __restrict__ out) {
    __shared__ float outs[4][64][16];   // [nb][v_local][k]  16 KB = 1024 float4
    const int blk = blockIdx.x;         // 2500
    const int nq = blk >> 1, vh = blk & 1;
    const int wv = threadIdx.x >> 6;
    const int vt = vh * 4 + wv;         // global v-tile 0..7
    const int lane = threadIdx.x & 63;
    const int l15 = lane & 15, lg = lane >> 4;
    const int n0 = nq * 4;              // 1250*4 = 5000 exact, no guards
    const int KSTART[4] = {0, 1, 4, 9};
    const int DP[4]     = {1, 3, 5, 7};
    const float inv = 0.08838834764831845f;

    for (int p = 0; p < 4; ++p) {
        const int kst = KSTART[p];
        f32x4 acc[4] = {{0,0,0,0},{0,0,0,0},{0,0,0,0},{0,0,0,0}};
#pragma unroll
        for (int ks = 0; ks < 4; ++ks) {
            size_t aoff = ((size_t)(p * 128 + vt * 16 + l15)) * 128 + ks * 32 + lg * 8;
            bf16x8 Ah = *(const bf16x8*)(wpth + aoff);
            bf16x8 Al = *(const bf16x8*)(wptl + aoff);
#pragma unroll
            for (int nb = 0; nb < 4; ++nb) {
                size_t boff = ((size_t)((n0 + nb) * 16 + kst + l15)) * 128 + ks * 32 + lg * 8;
                bf16x8 Bh = *(const bf16x8*)(toth + boff);
                bf16x8 Bl = *(const bf16x8*)(totl + boff);
                acc[nb] = __builtin_amdgcn_mfma_f32_16x16x32_bf16(Ah, Bh, acc[nb], 0, 0, 0);
                acc[nb] = __builtin_amdgcn_mfma_f32_16x16x32_bf16(Ah, Bl, acc[nb], 0, 0, 0);
                acc[nb] = __builtin_amdgcn_mfma_f32_16x16x32_bf16(Al, Bh, acc[nb], 0, 0, 0);
            }
        }
        if (l15 < DP[p]) {
            const int kg = kst + l15;
#pragma unroll
            for (int nb = 0; nb < 4; ++nb)
#pragma unroll
                for (int r = 0; r < 4; ++r)
                    outs[nb][wv * 16 + lg * 4 + r][kg] = acc[nb][r] * inv;
        }
    }
    __syncthreads();

    // coalesced write: 4 nodes x 64 v x 16 k = 4096 floats = 1024 float4
    const float4* src = (const float4*)outs;
    for (int i = threadIdx.x; i < 1024; i += 256) {
        int nb = i >> 8;            // 256 float4 per node
        int rem = i & 255;          // vl*4 + kq
        float4* dst = (float4*)(out + (size_t)(n0 + nb) * 2048 + (size_t)vh * 1024);
        dst[rem] = src[i];
    }
}

// ---------------- launch ----------------
extern "C" void kernel_launch(void* const* d_in, const int* in_sizes, int n_in,
                              void* d_out, int out_size, void* d_ws, size_t ws_size,
                              hipStream_t stream) {
    const float* nf    = (const float*)d_in[0];
    const float* sph   = (const float*)d_in[1];
    const float* rb    = (const float*)d_in[2];
    const int*   ei    = (const int*)d_in[3];
    const int*   ej    = (const int*)d_in[4];
    const float* Wpre  = (const float*)d_in[5];
    const float* w0    = (const float*)d_in[6];
    const float* w1    = (const float*)d_in[7];
    const float* w2    = (const float*)d_in[8];
    const float* w3    = (const float*)d_in[9];
    const float* Wpost = (const float*)d_in[10];
    float* out = (float*)d_out;

    char* ws = (char*)d_ws;
    const size_t OFF_X       = 0;
    const size_t OFF_WE      = 2560000;
    const size_t OFF_COUNTS  = 104960000;
    const size_t OFF_CURSOR  = 104980000;
    const size_t OFF_OFFSETS = 105000000;
    const size_t OFF_ORDER   = 105020032;
    const size_t OFF_W1H     = 105420032;
    const size_t OFF_W1L     = OFF_W1H + 8192;
    const size_t OFF_W2H     = OFF_W1L + 8192;
    const size_t OFF_W2L     = OFF_W2H + 8192;
    const size_t OFF_W3H     = OFF_W2L + 8192;
    const size_t OFF_W3L     = OFF_W3H + 65536;
    const size_t OFF_TOTH    = OFF_W3L + 65536;
    const size_t OFF_TOTL    = OFF_TOTH + 20484096;
    const size_t OFF_WPTH    = OFF_TOTL + 20484096;
    const size_t OFF_WPTL    = OFF_WPTH + 131072;
    const size_t NEEDED      = OFF_WPTL + 131072;
    if (ws_size < NEEDED) return;

    float* x       = (float*)(ws + OFF_X);
    u16*   we      = (u16*)(ws + OFF_WE);
    int*   counts  = (int*)(ws + OFF_COUNTS);
    int*   cursor  = (int*)(ws + OFF_CURSOR);
    int*   offsets = (int*)(ws + OFF_OFFSETS);
    int*   order   = (int*)(ws + OFF_ORDER);
    u16*   w1h = (u16*)(ws + OFF_W1H); u16* w1l = (u16*)(ws + OFF_W1L);
    u16*   w2h = (u16*)(ws + OFF_W2H); u16* w2l = (u16*)(ws + OFF_W2L);
    u16*   w3h = (u16*)(ws + OFF_W3H); u16* w3l = (u16*)(ws + OFF_W3L);
    u16*   toth = (u16*)(ws + OFF_TOTH);
    u16*   totl = (u16*)(ws + OFF_TOTL);
    u16*   wpth = (u16*)(ws + OFF_WPTH);
    u16*   wptl = (u16*)(ws + OFF_WPTL);

    (void)hipMemsetAsync(ws + OFF_COUNTS, 0, 40000, stream);

    k_count<<<(NE + 255) / 256, 256, 0, stream>>>(ei, counts);
    k_scan<<<1, 256, 0, stream>>>(counts, offsets);
    k_fill<<<(NE + 255) / 256, 256, 0, stream>>>(ei, offsets, cursor, order);
    k_wprep<<<128, 256, 0, stream>>>(w1, w2, w3, w1h, w1l, w2h, w2l, w3h, w3l);
    k_wpprep<<<256, 256, 0, stream>>>(Wpost, wpth, wptl);

    k_pre<<<NN, 128, 0, stream>>>(nf, Wpre, x);
    k_mlp<<<(NE + 63) / 64, 256, 0, stream>>>(rb, w0, w1h, w1l, w2h, w2l, w3h, w3l, we);
    k_gather<<<(NN + 3) / 4, 256, 0, stream>>>(x, we, sph, ej, offsets, order, toth, totl);
    k_post<<<2500, 256, 0, stream>>>(toth, totl, wpth, wptl, out);
}

// Round 9
// 274.454 us; speedup vs baseline: 1.4376x; 1.4376x over previous
//
#include <hip/hip_runtime.h>
#include <hip/hip_bf16.h>

#define NN 5000
#define NE 100000

typedef unsigned short u16;
typedef __attribute__((ext_vector_type(8))) short bf16x8;
typedef __attribute__((ext_vector_type(8))) unsigned short u16x8;
typedef __attribute__((ext_vector_type(4))) float f32x4;

__device__ __forceinline__ float silu_f(float x) {
    return x / (1.0f + __expf(-x));
}

__device__ __forceinline__ u16 f2bf(float x) {
    unsigned int u = __float_as_uint(x);
    u += 0x7FFFu + ((u >> 16) & 1u);
    return (u16)(u >> 16);
}
__device__ __forceinline__ float bf2f(u16 h) {
    return __uint_as_float(((unsigned int)h) << 16);
}

// ---------------- x = nf @ W_pre * (1/sqrt(128)) ----------------
__global__ __launch_bounds__(128) void k_pre(const float* __restrict__ nf,
                                             const float* __restrict__ Wpre,
                                             float* __restrict__ x) {
    __shared__ float row[128];
    int n = blockIdx.x;
    int v = threadIdx.x;
    row[v] = nf[(size_t)n * 128 + v];
    __syncthreads();
    float acc = 0.f;
#pragma unroll 16
    for (int u = 0; u < 128; ++u) acc += row[u] * Wpre[u * 128 + v];
    x[(size_t)n * 128 + v] = acc * 0.08838834764831845f;
}

// ---------------- CSR build (int atomics only) ----------------
__global__ void k_count(const int* __restrict__ ei, int* __restrict__ counts) {
    int e = blockIdx.x * blockDim.x + threadIdx.x;
    if (e < NE) atomicAdd(&counts[ei[e]], 1);
}

__global__ __launch_bounds__(256) void k_scan(const int* __restrict__ counts,
                                              int* __restrict__ offsets) {
    __shared__ int part[256];
    int t = threadIdx.x;
    const int CH = 20;
    int lo = t * CH, hi = min(lo + CH, NN);
    int s = 0;
    for (int i = lo; i < hi; ++i) s += counts[i];
    part[t] = s;
    __syncthreads();
    if (t == 0) {
        int run = 0;
        for (int i = 0; i < 256; ++i) { int v = part[i]; part[i] = run; run += v; }
    }
    __syncthreads();
    int run = part[t];
    for (int i = lo; i < hi; ++i) { offsets[i] = run; run += counts[i]; }
    if (t == 0) offsets[NN] = NE;
}

__global__ void k_fill(const int* __restrict__ ei, const int* __restrict__ offsets,
                       int* __restrict__ cursor, int* __restrict__ order) {
    int e = blockIdx.x * blockDim.x + threadIdx.x;
    if (e < NE) {
        int i = ei[e];
        int pos = atomicAdd(&cursor[i], 1);
        order[offsets[i] + pos] = e;
    }
}

// ---------------- weight prep: transpose + bf16 hi/lo split ----------------
__global__ __launch_bounds__(256) void k_wprep(const float* __restrict__ w1,
                                               const float* __restrict__ w2,
                                               const float* __restrict__ w3,
                                               u16* __restrict__ w1h, u16* __restrict__ w1l,
                                               u16* __restrict__ w2h, u16* __restrict__ w2l,
                                               u16* __restrict__ w3h, u16* __restrict__ w3l) {
    int i = blockIdx.x * 256 + threadIdx.x;
    if (i < 4096) {
        int k = i >> 6, n = i & 63;
        float v = w1[i];
        u16 h = f2bf(v), l = f2bf(v - bf2f(h));
        w1h[n * 64 + k] = h; w1l[n * 64 + k] = l;
        v = w2[i];
        h = f2bf(v); l = f2bf(v - bf2f(h));
        w2h[n * 64 + k] = h; w2l[n * 64 + k] = l;
    }
    if (i < 32768) {
        int k = i >> 9, n = i & 511;
        float v = w3[i];
        u16 h = f2bf(v), l = f2bf(v - bf2f(h));
        w3h[n * 64 + k] = h; w3l[n * 64 + k] = l;
    }
}

// Wpost^T hi/lo split: wpt[(p*128 + v)*128 + u]
__global__ __launch_bounds__(256) void k_wpprep(const float* __restrict__ Wpost,
                                                u16* __restrict__ wpth,
                                                u16* __restrict__ wptl) {
    int i = blockIdx.x * 256 + threadIdx.x;   // 65536
    int p = i >> 14, rem = i & 16383, u = rem >> 7, v = rem & 127;
    float val = Wpost[i];
    u16 h = f2bf(val), l = f2bf(val - bf2f(h));
    int o = (p * 128 + v) * 128 + u;
    wpth[o] = h; wptl[o] = l;
}

// ---------------- MFMA MLP layers ----------------
__device__ __forceinline__ void layer_mid(const char* s,
                                          const u16* __restrict__ wh,
                                          const u16* __restrict__ wl,
                                          char* d, int w, int l) {
    const int col = w * 16 + (l & 15);
    bf16x8 Bh[2], Bl[2];
#pragma unroll
    for (int kc = 0; kc < 2; ++kc) {
        Bh[kc] = *(const bf16x8*)(wh + col * 64 + kc * 32 + ((l >> 4) << 3));
        Bl[kc] = *(const bf16x8*)(wl + col * 64 + kc * 32 + ((l >> 4) << 3));
    }
#pragma unroll
    for (int rt = 0; rt < 4; ++rt) {
        const int arow = rt * 16 + (l & 15);
        f32x4 acc = {0.f, 0.f, 0.f, 0.f};
#pragma unroll
        for (int kc = 0; kc < 2; ++kc) {
            int off = (arow * 128 + kc * 64 + ((l >> 4) << 4)) ^ ((arow & 7) << 4);
            bf16x8 a = *(const bf16x8*)(s + off);
            acc = __builtin_amdgcn_mfma_f32_16x16x32_bf16(a, Bh[kc], acc, 0, 0, 0);
            acc = __builtin_amdgcn_mfma_f32_16x16x32_bf16(a, Bl[kc], acc, 0, 0, 0);
        }
#pragma unroll
        for (int r = 0; r < 4; ++r) {
            float v = silu_f(acc[r] * 0.125f);
            int orow = rt * 16 + ((l >> 4) << 2) + r;
            int off = (orow * 128 + col * 2) ^ ((orow & 7) << 4);
            *(u16*)(d + off) = f2bf(v);
        }
    }
}

// 64->512 output layer; store bf16 to global in [e][u][p] order.
__device__ __forceinline__ void layer_out(const char* s,
                                          const u16* __restrict__ wh,
                                          const u16* __restrict__ wl,
                                          u16* __restrict__ we, int base, int w, int l) {
    const int r0 = (w & 1) * 32;
    const int c0 = (w >> 1) * 256;
    bf16x8 A[2][2];
#pragma unroll
    for (int rt = 0; rt < 2; ++rt)
#pragma unroll
        for (int kc = 0; kc < 2; ++kc) {
            int row = r0 + rt * 16 + (l & 15);
            int off = (row * 128 + kc * 64 + ((l >> 4) << 4)) ^ ((row & 7) << 4);
            A[rt][kc] = *(const bf16x8*)(s + off);
        }
    for (int nt = 0; nt < 16; ++nt) {
        const int col = c0 + nt * 16 + (l & 15);
        f32x4 acc[2] = {{0.f, 0.f, 0.f, 0.f}, {0.f, 0.f, 0.f, 0.f}};
#pragma unroll
        for (int kc = 0; kc < 2; ++kc) {
            bf16x8 bh = *(const bf16x8*)(wh + col * 64 + kc * 32 + ((l >> 4) << 3));
            bf16x8 bl = *(const bf16x8*)(wl + col * 64 + kc * 32 + ((l >> 4) << 3));
#pragma unroll
            for (int rt = 0; rt < 2; ++rt) {
                acc[rt] = __builtin_amdgcn_mfma_f32_16x16x32_bf16(A[rt][kc], bh, acc[rt], 0, 0, 0);
                acc[rt] = __builtin_amdgcn_mfma_f32_16x16x32_bf16(A[rt][kc], bl, acc[rt], 0, 0, 0);
            }
        }
        const int up = ((col & 127) << 2) + (col >> 7);   // [u][p] position
#pragma unroll
        for (int rt = 0; rt < 2; ++rt)
#pragma unroll
            for (int r = 0; r < 4; ++r) {
                int row = r0 + rt * 16 + ((l >> 4) << 2) + r;
                int e = base + row;
                if (e < NE) we[(size_t)e * 512 + up] = f2bf(acc[rt][r] * 0.125f);
            }
    }
}

__global__ __launch_bounds__(256) void k_mlp(const float* __restrict__ rb,
                                             const float* __restrict__ w0,
                                             const u16* __restrict__ w1h, const u16* __restrict__ w1l,
                                             const u16* __restrict__ w2h, const u16* __restrict__ w2l,
                                             const u16* __restrict__ w3h, const u16* __restrict__ w3l,
                                             u16* __restrict__ we) {
    __shared__ __align__(16) char hA[8192];
    __shared__ __align__(16) char hB[8192];
    __shared__ float rbs[512];
    const int t = threadIdx.x;
    const int l = t & 63, w = t >> 6;
    const int base = blockIdx.x * 64;

    for (int i = t; i < 512; i += 256) {
        int e = base + (i >> 3);
        rbs[i] = (e < NE) ? rb[(size_t)e * 8 + (i & 7)] : 0.f;
    }
    __syncthreads();

    {
        const int m = t >> 2, n0 = (t & 3) * 16;
        float h[16];
#pragma unroll
        for (int nn = 0; nn < 16; ++nn) h[nn] = 0.f;
#pragma unroll
        for (int k = 0; k < 8; ++k) {
            float r = rbs[m * 8 + k];
            const float* wp = w0 + k * 64 + n0;
#pragma unroll
            for (int nn = 0; nn < 16; ++nn) h[nn] += r * wp[nn];
        }
#pragma unroll
        for (int nn = 0; nn < 16; ++nn) {
            float v = silu_f(h[nn] * 0.35355339059327373f);
            int off = (m * 128 + (n0 + nn) * 2) ^ ((m & 7) << 4);
            *(u16*)(hA + off) = f2bf(v);
        }
    }
    __syncthreads();
    layer_mid(hA, w1h, w1l, hB, w, l);
    __syncthreads();
    layer_mid(hB, w2h, w2l, hA, w, l);
    __syncthreads();
    layer_out(hA, w3h, w3l, we, base, w, l);
}

// ---------------- Phase A: per-node segment sum (1 wave per node) ----------------
// EXACT round-6 verified version: writes tot hi/lo to GLOBAL, layout (n*16+k)*128+u.
__global__ __launch_bounds__(256) void k_gather(const float* __restrict__ x,
                                                const u16* __restrict__ we,
                                                const float* __restrict__ sph,
                                                const int* __restrict__ ej,
                                                const int* __restrict__ offsets,
                                                const int* __restrict__ order,
                                                u16* __restrict__ toth,
                                                u16* __restrict__ totl) {
    const int lane = threadIdx.x & 63;
    const int n = blockIdx.x * 4 + (threadIdx.x >> 6);
    if (n >= NN) return;
    const int s0 = offsets[n], s1 = offsets[n + 1];

    float acc0[16] = {};
    float acc1[16] = {};
    const int PMAP[16] = {0,1,1,1, 2,2,2,2, 2,3,3,3, 3,3,3,3};

    for (int base = s0; base < s1; base += 64) {
        int idx = base + lane;
        int ev = (idx < s1) ? order[idx] : 0;
        int jv = (idx < s1) ? ej[ev] : 0;
        int cnt = min(64, s1 - base);
        for (int i = 0; i < cnt; ++i) {
            int e = __shfl(ev, i);
            int j = __shfl(jv, i);
            const float* xp = x + (size_t)j * 128;
            float xj0 = xp[lane];
            float xj1 = xp[lane + 64];
            const u16* wep = we + (size_t)e * 512;
            ushort4 w0v = *(const ushort4*)(wep + lane * 4);
            ushort4 w1v = *(const ushort4*)(wep + (lane + 64) * 4);
            float a0[4] = {xj0 * bf2f(w0v.x), xj0 * bf2f(w0v.y),
                           xj0 * bf2f(w0v.z), xj0 * bf2f(w0v.w)};
            float a1[4] = {xj1 * bf2f(w1v.x), xj1 * bf2f(w1v.y),
                           xj1 * bf2f(w1v.z), xj1 * bf2f(w1v.w)};
            const float4* Y4 = (const float4*)(sph + (size_t)e * 16);
            float yv[16];
            ((float4*)yv)[0] = Y4[0];
            ((float4*)yv)[1] = Y4[1];
            ((float4*)yv)[2] = Y4[2];
            ((float4*)yv)[3] = Y4[3];
#pragma unroll
            for (int k = 0; k < 16; ++k) {
                acc0[k] += a0[PMAP[k]] * yv[k];
                acc1[k] += a1[PMAP[k]] * yv[k];
            }
        }
    }

#pragma unroll
    for (int k = 0; k < 16; ++k) {
        size_t o = ((size_t)n * 16 + k) * 128;
        u16 h0 = f2bf(acc0[k]);
        toth[o + lane] = h0;
        totl[o + lane] = f2bf(acc0[k] - bf2f(h0));
        u16 h1 = f2bf(acc1[k]);
        toth[o + 64 + lane] = h1;
        totl[o + 64 + lane] = f2bf(acc1[k] - bf2f(h1));
    }
}

// ---------------- Phase B: coalesced LDS staging + MFMA epilogue ----------------
// Block = 4 nodes. Stage tot[4 nodes][16 k][128 u] hi/lo into LDS (k*136+u),
// then round-8 post phase: wave wv -> vt = wv*2+{0,1}, B-fragments from LDS.
__global__ __launch_bounds__(256) void k_post(const u16* __restrict__ toth,
                                              const u16* __restrict__ totl,
                                              const u16* __restrict__ wpth,
                                              const u16* __restrict__ wptl,
                                              float* __restrict__ out) {
    __shared__ __align__(16) u16 tot_h[4][2176];
    __shared__ __align__(16) u16 tot_l[4][2176];
    __shared__ __align__(16) float stage[4][4][16][16];
    const int lane = threadIdx.x & 63;
    const int wv = threadIdx.x >> 6;
    const int n0 = blockIdx.x * 4;   // 1250 blocks * 4 = 5000 exact

    // coalesced staging: per node 2048 u16 = 256 chunks of 8
    for (int i = threadIdx.x; i < 1024; i += 256) {
        int nb = i >> 8;
        int rem = i & 255;
        int k = rem >> 4, u8 = (rem & 15) << 3;
        size_t g = (size_t)(n0 + nb) * 2048 + rem * 8;
        *(u16x8*)&tot_h[nb][k * 136 + u8] = *(const u16x8*)(toth + g);
        *(u16x8*)&tot_l[nb][k * 136 + u8] = *(const u16x8*)(totl + g);
    }
    __syncthreads();

    const int l15 = lane & 15, lg = lane >> 4;
    const int KSTART[4] = {0, 1, 4, 9};
    const int DP[4]     = {1, 3, 5, 7};
    const float inv = 0.08838834764831845f;

    for (int vi = 0; vi < 2; ++vi) {
        const int vt = wv * 2 + vi;
        for (int p = 0; p < 4; ++p) {
            const int kst = KSTART[p];
            int kr = kst + l15; if (kr > 15) kr = 15;   // clamp: only discarded cols affected
            f32x4 acc[4] = {{0,0,0,0},{0,0,0,0},{0,0,0,0},{0,0,0,0}};
#pragma unroll
            for (int ks = 0; ks < 4; ++ks) {
                size_t aoff = ((size_t)(p * 128 + vt * 16 + l15)) * 128 + ks * 32 + lg * 8;
                bf16x8 Ah = *(const bf16x8*)(wpth + aoff);
                bf16x8 Al = *(const bf16x8*)(wptl + aoff);
                int bidx = kr * 136 + ks * 32 + lg * 8;
#pragma unroll
                for (int nb = 0; nb < 4; ++nb) {
                    bf16x8 Bh = *(const bf16x8*)(&tot_h[nb][bidx]);
                    bf16x8 Bl = *(const bf16x8*)(&tot_l[nb][bidx]);
                    acc[nb] = __builtin_amdgcn_mfma_f32_16x16x32_bf16(Ah, Bh, acc[nb], 0, 0, 0);
                    acc[nb] = __builtin_amdgcn_mfma_f32_16x16x32_bf16(Ah, Bl, acc[nb], 0, 0, 0);
                    acc[nb] = __builtin_amdgcn_mfma_f32_16x16x32_bf16(Al, Bh, acc[nb], 0, 0, 0);
                }
            }
            if (l15 < DP[p]) {
                const int kg = kst + l15;
#pragma unroll
                for (int nb = 0; nb < 4; ++nb)
#pragma unroll
                    for (int r = 0; r < 4; ++r)
                        stage[wv][nb][lg * 4 + r][kg] = acc[nb][r] * inv;
            }
        }
        __syncthreads();
#pragma unroll
        for (int nb = 0; nb < 4; ++nb) {
            const float4 vle = *(const float4*)&stage[wv][nb][lane >> 2][(lane & 3) * 4];
            *(float4*)&out[(size_t)(n0 + nb) * 2048 + vt * 256 + (lane >> 2) * 16 + (lane & 3) * 4] = vle;
        }
        __syncthreads();
    }
}

// ---------------- launch ----------------
extern "C" void kernel_launch(void* const* d_in, const int* in_sizes, int n_in,
                              void* d_out, int out_size, void* d_ws, size_t ws_size,
                              hipStream_t stream) {
    const float* nf    = (const float*)d_in[0];
    const float* sph   = (const float*)d_in[1];
    const float* rb    = (const float*)d_in[2];
    const int*   ei    = (const int*)d_in[3];
    const int*   ej    = (const int*)d_in[4];
    const float* Wpre  = (const float*)d_in[5];
    const float* w0    = (const float*)d_in[6];
    const float* w1    = (const float*)d_in[7];
    const float* w2    = (const float*)d_in[8];
    const float* w3    = (const float*)d_in[9];
    const float* Wpost = (const float*)d_in[10];
    float* out = (float*)d_out;

    char* ws = (char*)d_ws;
    const size_t OFF_X       = 0;
    const size_t OFF_WE      = 2560000;
    const size_t OFF_COUNTS  = 104960000;
    const size_t OFF_CURSOR  = 104980000;
    const size_t OFF_OFFSETS = 105000000;
    const size_t OFF_ORDER   = 105020032;
    const size_t OFF_W1H     = 105420032;
    const size_t OFF_W1L     = OFF_W1H + 8192;
    const size_t OFF_W2H     = OFF_W1L + 8192;
    const size_t OFF_W2L     = OFF_W2H + 8192;
    const size_t OFF_W3H     = OFF_W2L + 8192;
    const size_t OFF_W3L     = OFF_W3H + 65536;
    const size_t OFF_WPTH    = OFF_W3L + 65536;
    const size_t OFF_WPTL    = OFF_WPTH + 131072;
    const size_t OFF_TOTH    = OFF_WPTL + 131072;      // 20,480,000 each
    const size_t OFF_TOTL    = OFF_TOTH + 20480000;
    const size_t NEEDED      = OFF_TOTL + 20480000;
    if (ws_size < NEEDED) return;

    float* x       = (float*)(ws + OFF_X);
    u16*   we      = (u16*)(ws + OFF_WE);
    int*   counts  = (int*)(ws + OFF_COUNTS);
    int*   cursor  = (int*)(ws + OFF_CURSOR);
    int*   offsets = (int*)(ws + OFF_OFFSETS);
    int*   order   = (int*)(ws + OFF_ORDER);
    u16*   w1h = (u16*)(ws + OFF_W1H); u16* w1l = (u16*)(ws + OFF_W1L);
    u16*   w2h = (u16*)(ws + OFF_W2H); u16* w2l = (u16*)(ws + OFF_W2L);
    u16*   w3h = (u16*)(ws + OFF_W3H); u16* w3l = (u16*)(ws + OFF_W3L);
    u16*   wpth = (u16*)(ws + OFF_WPTH);
    u16*   wptl = (u16*)(ws + OFF_WPTL);
    u16*   toth = (u16*)(ws + OFF_TOTH);
    u16*   totl = (u16*)(ws + OFF_TOTL);

    (void)hipMemsetAsync(ws + OFF_COUNTS, 0, 40000, stream);

    k_count<<<(NE + 255) / 256, 256, 0, stream>>>(ei, counts);
    k_scan<<<1, 256, 0, stream>>>(counts, offsets);
    k_fill<<<(NE + 255) / 256, 256, 0, stream>>>(ei, offsets, cursor, order);
    k_wprep<<<128, 256, 0, stream>>>(w1, w2, w3, w1h, w1l, w2h, w2l, w3h, w3l);
    k_wpprep<<<256, 256, 0, stream>>>(Wpost, wpth, wptl);

    k_pre<<<NN, 128, 0, stream>>>(nf, Wpre, x);
    k_mlp<<<(NE + 63) / 64, 256, 0, stream>>>(rb, w0, w1h, w1l, w2h, w2l, w3h, w3l, we);
    k_gather<<<(NN + 3) / 4, 256, 0, stream>>>(x, we, sph, ej, offsets, order, toth, totl);
    k_post<<<NN / 4, 256, 0, stream>>>(toth, totl, wpth, wptl, out);
}